// Round 4
// baseline (129.161 us; speedup 1.0000x reference)
//
#include <hip/hip_runtime.h>

#define W 1024
#define H 1024
#define NIMG 64
#define NBINS 256
#define NPIX (W * H)                       // per image
#define NTOT ((long long)NIMG * NPIX)      // 67108864
#define HBLK 64                            // hist blocks per image
#define RPW 16                             // rows per wave (lap)
#define LGRIDX (H / (RPW * 4))             // 16 lap blocks per image

typedef float f32x4 __attribute__((ext_vector_type(4)));

// workspace layout (bytes) — every byte used is fully written each launch,
// so no memset/zeroing dispatch is needed (poison-safe, graph-safe):
//   [0,       4 MB)   partial hists:  [NIMG][HBLK][NBINS] u32
//   [4 MB,   +64 KB)  lut32:          [NIMG][NBINS] u32 (eq value 0..255)
//   [4 MB+64K,+16 KB) acc:            [NIMG*LGRIDX][2] u64
//   [8 MB,   +64 MB)  u8 image
#define WS_PART 0
#define WS_LUT  (4u * 1024 * 1024)
#define WS_ACC  (WS_LUT + 64 * 1024)
#define WS_U8   (8u * 1024 * 1024)

__global__ __launch_bounds__(256) void hist_kernel(const float* __restrict__ img,
                                                   unsigned int* __restrict__ part,
                                                   unsigned char* __restrict__ u8img) {
    __shared__ unsigned int lh[NBINS];
    const int b = blockIdx.y;
    lh[threadIdx.x] = 0u;
    __syncthreads();
    const size_t base = (size_t)b * NPIX;
    const f32x4* p = (const f32x4*)(img + base);
    uchar4* q8 = (uchar4*)(u8img + base);
    const int nvec = NPIX / 4;
    const int stride = gridDim.x * 256;
    for (int i = blockIdx.x * 256 + threadIdx.x; i < nvec; i += stride) {
        f32x4 v = __builtin_nontemporal_load(&p[i]);
        int i0 = min(max((int)v[0], 0), 255);
        int i1 = min(max((int)v[1], 0), 255);
        int i2 = min(max((int)v[2], 0), 255);
        int i3 = min(max((int)v[3], 0), 255);
        atomicAdd(&lh[i0], 1u);
        atomicAdd(&lh[i1], 1u);
        atomicAdd(&lh[i2], 1u);
        atomicAdd(&lh[i3], 1u);
        q8[i] = make_uchar4((unsigned char)i0, (unsigned char)i1,
                            (unsigned char)i2, (unsigned char)i3);
    }
    __syncthreads();
    // plain coalesced store of the per-block partial histogram (no init needed)
    part[((size_t)b * HBLK + blockIdx.x) * NBINS + threadIdx.x] = lh[threadIdx.x];
}

__global__ __launch_bounds__(256) void lut_kernel(const unsigned int* __restrict__ part,
                                                  unsigned int* __restrict__ lut32) {
    __shared__ float cdf[NBINS];
    __shared__ float s_min;
    const int b = blockIdx.x;
    const int t = threadIdx.x;
    unsigned int h = 0;
#pragma unroll 8
    for (int blk = 0; blk < HBLK; ++blk)
        h += part[((size_t)b * HBLK + blk) * NBINS + t];
    cdf[t] = (float)h;
    __syncthreads();
    for (int off = 1; off < NBINS; off <<= 1) {
        float add = (t >= off) ? cdf[t - off] : 0.0f;
        __syncthreads();
        cdf[t] += add;
        __syncthreads();
    }
    if (t == 0) {
        float m = 0.0f;
        for (int i = 0; i < NBINS; ++i) {
            if (cdf[i] > 0.0f) { m = cdf[i]; break; }
        }
        s_min = m;
    }
    __syncthreads();
    const float scale = 255.0f / fmaxf((float)NPIX - s_min, 1.0f);
    float L = fminf(fmaxf(rintf((cdf[t] - s_min) * scale), 0.0f), 255.0f);
    lut32[b * NBINS + t] = (unsigned int)L;
}

// lap: one wave per RPW-row strip; lane owns 16 consecutive px; eq rows held
// unpacked (int per px) in a 3-row register pipeline; LUT gather = one LDS
// u32 read per pixel; left/right wave edges via shfl; raw row prefetched one
// iteration ahead to hide L3/HBM latency.
__global__ __launch_bounds__(256) void lap_kernel(const unsigned char* __restrict__ u8img,
                                                  const unsigned int* __restrict__ lut32,
                                                  unsigned long long* __restrict__ acc) {
    __shared__ unsigned int slut[NBINS];
    const int b = blockIdx.y;
    slut[threadIdx.x] = lut32[b * NBINS + threadIdx.x];
    __syncthreads();

    const int lane = threadIdx.x & 63;
    const int wv = threadIdx.x >> 6;
    const int y0 = blockIdx.x * (RPW * 4) + wv * RPW;
    const unsigned char* rowp = u8img + (size_t)b * NPIX + lane * 16;

    int pr[16], cr[16], nr[16];

    auto load_raw = [&](int gy, uint4& raw) {
        if ((unsigned)gy < (unsigned)H) raw = *(const uint4*)(rowp + (size_t)gy * W);
        else raw = make_uint4(0u, 0u, 0u, 0u);
    };
    auto gather = [&](const uint4& raw, bool valid, int out[16]) {
        const unsigned int w[4] = {raw.x, raw.y, raw.z, raw.w};
        if (valid) {
#pragma unroll
            for (int k = 0; k < 4; ++k)
#pragma unroll
                for (int j = 0; j < 4; ++j)
                    out[4 * k + j] = (int)slut[(w[k] >> (8 * j)) & 0xFFu];
        } else {
#pragma unroll
            for (int p = 0; p < 16; ++p) out[p] = 0;
        }
    };

    uint4 rawC, rawN;
    load_raw(y0 - 1, rawC);
    gather(rawC, y0 - 1 >= 0, pr);
    load_raw(y0, rawC);
    gather(rawC, true, cr);
    load_raw(y0 + 1, rawC);

    int s = 0, q = 0;   // q max: 16*16*1020^2 = 2.66e8 < 2^31
#pragma unroll
    for (int rr = 0; rr < RPW; ++rr) {
        const int gy = y0 + rr;
        load_raw(gy + 2, rawN);                 // prefetch one row ahead
        gather(rawC, gy + 1 < H, nr);

        int lw = __shfl_up(cr[15], 1, 64);
        lw = (lane == 0) ? 0 : lw;
        int rw = __shfl_down(cr[0], 1, 64);
        rw = (lane == 63) ? 0 : rw;

#pragma unroll
        for (int p = 0; p < 16; ++p) {
            const int l = (p == 0) ? lw : cr[p - 1];
            const int r = (p == 15) ? rw : cr[p + 1];
            const int lap = pr[p] + nr[p] + l + r - 4 * cr[p];
            s += lap;
            q += lap * lap;
        }
#pragma unroll
        for (int p = 0; p < 16; ++p) { pr[p] = cr[p]; cr[p] = nr[p]; }
        rawC = rawN;
    }

    long long S = s, Q = q;
    for (int off = 32; off > 0; off >>= 1) {
        S += __shfl_down(S, off, 64);
        Q += __shfl_down(Q, off, 64);
    }
    __shared__ long long ss[4], sq[4];
    if (lane == 0) { ss[wv] = S; sq[wv] = Q; }
    __syncthreads();
    if (threadIdx.x == 0) {
        long long St = ss[0] + ss[1] + ss[2] + ss[3];
        long long Qt = sq[0] + sq[1] + sq[2] + sq[3];
        const int blk = blockIdx.x + blockIdx.y * gridDim.x;   // [0, 1024)
        acc[2 * blk]     = (unsigned long long)St;             // unconditional write
        acc[2 * blk + 1] = (unsigned long long)Qt;
    }
}

__global__ __launch_bounds__(256) void finalize_kernel(const unsigned long long* __restrict__ acc,
                                                       float* __restrict__ out) {
    const int t = threadIdx.x;
    long long S = 0, Q = 0;
#pragma unroll
    for (int i = 0; i < NIMG * LGRIDX; i += 256) {
        S += (long long)acc[2 * (i + t)];
        Q += (long long)acc[2 * (i + t) + 1];
    }
    for (int off = 32; off > 0; off >>= 1) {
        S += __shfl_down(S, off, 64);
        Q += __shfl_down(Q, off, 64);
    }
    __shared__ long long ss[4], sq[4];
    const int wave = t >> 6, lane = t & 63;
    if (lane == 0) { ss[wave] = S; sq[wave] = Q; }
    __syncthreads();
    if (t == 0) {
        long long St = ss[0] + ss[1] + ss[2] + ss[3];
        long long Qt = sq[0] + sq[1] + sq[2] + sq[3];
        // lap = lap_int / 255 exactly; var = (Q/255^2 - (S/255)^2/N) / (N-1)
        const double N = (double)NTOT;
        double Sr = (double)St / 255.0;
        double Qr = (double)Qt / 65025.0;
        out[0] = (float)((Qr - Sr * Sr / N) / (N - 1.0));
    }
}

extern "C" void kernel_launch(void* const* d_in, const int* in_sizes, int n_in,
                              void* d_out, int out_size, void* d_ws, size_t ws_size,
                              hipStream_t stream) {
    const float* img = (const float*)d_in[0];
    float* out = (float*)d_out;

    unsigned int* part      = (unsigned int*)((char*)d_ws + WS_PART);
    unsigned int* lut32     = (unsigned int*)((char*)d_ws + WS_LUT);
    unsigned long long* acc = (unsigned long long*)((char*)d_ws + WS_ACC);
    unsigned char* u8img    = (unsigned char*)((char*)d_ws + WS_U8);

    dim3 hgrid(HBLK, NIMG);
    hist_kernel<<<hgrid, 256, 0, stream>>>(img, part, u8img);

    lut_kernel<<<NIMG, NBINS, 0, stream>>>(part, lut32);

    dim3 lgrid(LGRIDX, NIMG);
    lap_kernel<<<lgrid, 256, 0, stream>>>(u8img, lut32, acc);

    finalize_kernel<<<1, 256, 0, stream>>>(acc, out);
}